// Round 16
// baseline (49.448 us; speedup 1.0000x reference)
//
#include <hip/hip_runtime.h>

// LSHAttention: reference returns ONLY sticker = argsort(buckets) [B,S] int32.
// B=4, S=4096, D=1024, NR=32, 64 buckets.
//
// ROUND 16: Q NEVER TOUCHES LDS. R11's verified math, but Q is loaded
// global->VGPR in the hot loop (per wave+token-step: 2 cache lines, 4x lane
// dedup broadcast). Only R (16 KB/tile) is LDS-staged via global_load_lds
// double-buffer. One barrier per tile. LDS 34.4 KB -> 4 blocks/CU with
// 256-thr blocks = 16 waves/CU (R7-R15 all ran lower and were latency-dead:
// every no-spill variant measured ~40us with all pipes <=25% busy).
//
// k1: grid 1024 = (b:4, ch:256 -> 16 tokens), 256 thr = 4 waves, full K.
//   Thread = (tok_t:2 x8tok, r_t:4 x8r, kl:8); kq = w*8+kl; 4 k per thread
//   per 128-k tile; acc = 8tok x 8r = 64 f32.
//   Per tile: QLOAD 8xf4 (global, coalesced) ; ISSUE_R(tau+1) 4 DMA ;
//   FMA (compiler FIFO-vmcnt leaves DMA in flight) ; vmcnt0+lgkm0+barrier.
//   R LDS slot = k*8 + (rq ^ ((k>>2)&7)) via pre-swizzled DMA source (R11).
//   Epilogue: shfl_xor(1,2,4) kl-reduce, 4-slice LDS sum, argmax, 16-tok hist.
// k2: offset scan (256 chunks); k3: stable scatter (verified R11/R14 verbatim).

#define B_DIM 4
#define S_LEN 4096
#define D_DIM 1024
#define NRR 32
#define NBK 64
#define TMK 16                  // tokens per block = hist chunk
#define NCH (S_LEN / TMK)       // 256 chunks
#define NT 8                    // K-tiles of 128

typedef const __attribute__((address_space(1))) void* gas_t;
typedef __attribute__((address_space(3))) void* las_t;

__global__ void __launch_bounds__(256) __attribute__((amdgpu_waves_per_eu(2, 4)))
k1_buckets(const float* __restrict__ Q, const float* __restrict__ R,
           int* __restrict__ buckets, int* __restrict__ hist)
{
    __shared__ float4 smem4[2048];   // R0[0,1024) R1[1024,2048); slices reuse R0
    __shared__ float xs[TMK * 33];
    __shared__ int cnt[NBK];

    const int t = threadIdx.x;
    const int b = blockIdx.x >> 8;
    const int ch = blockIdx.x & 255;

    const int w = t >> 6;
    const int lane = t & 63;
    const int tok_t = lane >> 5;        // 2 groups x 8 tokens
    const int r_t = (lane >> 3) & 3;    // 4 groups x 8 r (2 f4)
    const int kl = lane & 7;            // 8-way k split in wave
    const int kq = w * 8 + kl;          // k-quad within tile [0,32)
    const int dwb = t & ~63;            // wave-uniform DMA dest base (f4)
    const int rsw0 = (r_t * 2 + 0) ^ kl;
    const int rsw1 = (r_t * 2 + 1) ^ kl;
    const int roff = kq * 32;           // + kk*8 + rsw

    const float4* Qg4 = (const float4*)(Q + ((size_t)b * S_LEN + ch * TMK) * D_DIM);
    const float4* Rg4 = (const float4*)(R + (size_t)b * D_DIM * NRR);

#define ISSUE_R(TILE, D)                                                      \
    {                                                                         \
        _Pragma("unroll")                                                     \
        for (int i = 0; i < 4; ++i) {                                         \
            const int f = t + 256 * i;                                        \
            __builtin_amdgcn_global_load_lds(                                 \
                (gas_t)(Rg4 + ((size_t)(TILE) * 128 + (f >> 3)) * 8           \
                        + ((f & 7) ^ ((f >> 5) & 7))),                        \
                (las_t)&smem4[(D) * 1024 + (i << 8) + dwb], 16, 0, 0);        \
        }                                                                     \
    }

    float4 acc[8][2];
#pragma unroll
    for (int j = 0; j < 8; ++j) {
        acc[j][0] = make_float4(0.f, 0.f, 0.f, 0.f);
        acc[j][1] = make_float4(0.f, 0.f, 0.f, 0.f);
    }
    if (t < NBK) cnt[t] = 0;

    // prologue: R tile 0
    ISSUE_R(0, 0)
    asm volatile("s_waitcnt vmcnt(0)\n\ts_barrier" ::: "memory");

    for (int tau = 0; tau < NT; ++tau) {
        // ---- Q: global -> regs, coalesced (2 lines per wave per j) ----
        float4 qv[8];
#pragma unroll
        for (int j = 0; j < 8; ++j)
            qv[j] = Qg4[(size_t)(tok_t * 8 + j) * 256 + tau * 32 + kq];

        // ---- next R tile DMA (newer than qv: FIFO vmcnt keeps it in flight) ----
        if (tau + 1 < NT) ISSUE_R(tau + 1, (tau + 1) & 1)

        // ---- compute on R buffer tau&1 ----
        {
            const float4* rb = smem4 + (tau & 1) * 1024;
            float4 rv[4][2];
#pragma unroll
            for (int kk = 0; kk < 4; ++kk) {
                rv[kk][0] = rb[roff + kk * 8 + rsw0];
                rv[kk][1] = rb[roff + kk * 8 + rsw1];
            }
#pragma unroll
            for (int j = 0; j < 8; ++j) {
#pragma unroll
                for (int kk = 0; kk < 4; ++kk) {
                    const float s = kk == 0 ? qv[j].x : kk == 1 ? qv[j].y
                                  : kk == 2 ? qv[j].z : qv[j].w;
#pragma unroll
                    for (int p = 0; p < 2; ++p) {
                        acc[j][p].x = fmaf(s, rv[kk][p].x, acc[j][p].x);
                        acc[j][p].y = fmaf(s, rv[kk][p].y, acc[j][p].y);
                        acc[j][p].z = fmaf(s, rv[kk][p].z, acc[j][p].z);
                        acc[j][p].w = fmaf(s, rv[kk][p].w, acc[j][p].w);
                    }
                }
            }
        }
        // one barrier per tile: my DMA landed (RAW for tau+1) + my ds_reads
        // of this buffer done (WAR vs tau+2's DMA, issued after this point)
        asm volatile("s_waitcnt vmcnt(0) lgkmcnt(0)\n\ts_barrier" ::: "memory");
    }
#undef ISSUE_R

    // ---- reduce over kl (lane bits 0-2): lanes kl==0 hold wave partial ----
#pragma unroll
    for (int j = 0; j < 8; ++j)
#pragma unroll
        for (int p = 0; p < 2; ++p) {
#pragma unroll
            for (int off = 1; off < 8; off <<= 1) {
                acc[j][p].x += __shfl_xor(acc[j][p].x, off, 64);
                acc[j][p].y += __shfl_xor(acc[j][p].y, off, 64);
                acc[j][p].z += __shfl_xor(acc[j][p].z, off, 64);
                acc[j][p].w += __shfl_xor(acc[j][p].w, off, 64);
            }
        }

    // ---- dump 4 wave-slices [16 tok][8 rq f4] into smem4[0,512) ----
    if (kl == 0) {
#pragma unroll
        for (int j = 0; j < 8; ++j) {
            const int tok = tok_t * 8 + j;
            smem4[w * 128 + tok * 8 + r_t * 2 + 0] = acc[j][0];
            smem4[w * 128 + tok * 8 + r_t * 2 + 1] = acc[j][1];
        }
    }
    __syncthreads();

    // ---- sum 4 slices (128 f4 positions) ----
    if (t < 128) {
        float4 s = smem4[t];
#pragma unroll
        for (int ww = 1; ww < 4; ++ww) {
            const float4 v = smem4[ww * 128 + t];
            s.x += v.x; s.y += v.y; s.z += v.z; s.w += v.w;
        }
        const int tok = t >> 3, rq = t & 7;
        xs[tok * 33 + rq * 4 + 0] = s.x;
        xs[tok * 33 + rq * 4 + 1] = s.y;
        xs[tok * 33 + rq * 4 + 2] = s.z;
        xs[tok * 33 + rq * 4 + 3] = s.w;
    }
    __syncthreads();

    if (t < TMK) {
        // argmax(concat[xR,-xR]) with first-occurrence tie-break
        float m1 = xs[t * 33 + 0]; int i1 = 0;
        float m2 = m1;             int i2 = 0;
#pragma unroll
        for (int r = 1; r < NRR; ++r) {
            const float v = xs[t * 33 + r];
            if (v > m1) { m1 = v; i1 = r; }
            if (v < m2) { m2 = v; i2 = r; }
        }
        const int bk = (m1 >= -m2) ? i1 : (NRR + i2);
        buckets[(size_t)b * S_LEN + ch * TMK + t] = bk;
        atomicAdd(&cnt[bk], 1);
    }
    __syncthreads();
    if (t < NBK) hist[((size_t)b * NCH + ch) * NBK + t] = cnt[t];
}

// One block, 256 threads: thread = (batch b = t/64, bucket bk = t%64).
__global__ __launch_bounds__(256) void k2_scan(
    const int* __restrict__ hist, int* __restrict__ chunkOffset)
{
    const int t = threadIdx.x;
    const int b = t >> 6;
    const int bk = t & 63;
    const int lane = t & 63;

    int total = 0;
    for (int c = 0; c < NCH; ++c)
        total += hist[((size_t)b * NCH + c) * NBK + bk];

    int incl = total;
#pragma unroll
    for (int off = 1; off < 64; off <<= 1) {
        int n = __shfl_up(incl, off, 64);
        if (lane >= off) incl += n;
    }
    int run = incl - total;   // exclusive prefix over buckets = bucketStart

    for (int c = 0; c < NCH; ++c) {
        int h = hist[((size_t)b * NCH + c) * NBK + bk];
        chunkOffset[((size_t)b * NCH + c) * NBK + bk] = run;
        run += h;
    }
}

// Stable scatter: 16-token chunks; rank via ballot within own 16-lane subgroup.
__global__ __launch_bounds__(256) void k3_scatter(
    const int* __restrict__ buckets, const int* __restrict__ chunkOffset,
    int* __restrict__ out)
{
    const int gid = blockIdx.x * 256 + threadIdx.x;  // 0..16383
    const int b = gid >> 12;
    const int s = gid & (S_LEN - 1);
    const int chunk = s >> 4;                        // 16-token chunk
    const int lane = threadIdx.x & 63;

    const int bk = buckets[gid];

    unsigned long long m = ~0ull;
#pragma unroll
    for (int i = 0; i < 6; ++i) {
        unsigned long long bi = __ballot((bk >> i) & 1);
        m &= ((bk >> i) & 1) ? bi : ~bi;
    }
    const unsigned int m16 = (unsigned int)((m >> (lane & 48)) & 0xFFFFull);
    const int rank = __popc(m16 & ((1u << (lane & 15)) - 1u));

    const int pos = chunkOffset[((size_t)b * NCH + chunk) * NBK + bk] + rank;
    out[(size_t)b * S_LEN + pos] = s;
}

extern "C" void kernel_launch(void* const* d_in, const int* in_sizes, int n_in,
                              void* d_out, int out_size, void* d_ws, size_t ws_size,
                              hipStream_t stream) {
    const float* Q = (const float*)d_in[0];
    // d_in[1] = key, d_in[2] = value: dead code in the reference, never read.
    const float* R = (const float*)d_in[3];

    int* buckets     = (int*)d_ws;                      // 16384 ints
    int* hist        = buckets + B_DIM * S_LEN;         // 4*256*64 = 65536 ints
    int* chunkOffset = hist + B_DIM * NCH * NBK;        // 65536 ints

    k1_buckets<<<B_DIM * NCH, 256, 0, stream>>>(Q, R, buckets, hist);
    k2_scan   <<<1,           256, 0, stream>>>(hist, chunkOffset);
    k3_scatter<<<(B_DIM * S_LEN) / 256, 256, 0, stream>>>(buckets, chunkOffset, (int*)d_out);
}

// Round 17
// 41.035 us; speedup vs baseline: 1.2050x; 1.2050x over previous
//
#include <hip/hip_runtime.h>

// LSHAttention: reference returns ONLY sticker = argsort(buckets) [B,S] int32.
// B=4, S=4096, D=1024, NR=32, 64 buckets.
//
// ROUND 17 = ROUND 12's barrier-free structure (best: 39.98us, waves own
// disjoint tokens + wave-private Q dbuf + shared read-only R), K-QUARTERED so
// TWO blocks fit per CU (R12 ran 1 wave/SIMD; all six no-spill variants
// plateaued 40-46us with every pipe <=25% busy -> missing factor = concurrent
// chains per SIMD).
//
// k1: grid 1024 = (b:4, chunk:64 -> 64 tok, kqr:4 -> 256 k), 256 thr = 4 waves.
//   Wave w owns tokens [w*16, w*16+16), full 256-k quarter. LDS = R quarter
//   32KB (staged once, read-only) + 4x wave-private Q dbuf (2x1KB f4) = 64KB
//   -> 2 blocks/CU. ONE barrier total; loop self-paced per wave:
//   lgkmcnt(0); ISSUE_Q(tau+1); COMPUTE(tau); vmcnt(0).
//   Lane = (tok_t:2 x8tok, r_t:4 x8r, kl:8 k-split); acc = 8tok x 8r = 64 f32.
//   Swizzles = R12 verbatim (Q slot sd^(tok>>3), R f4 v^((kh>>3)&7), both via
//   pre-swizzled DMA source; measured ~1M conflict-cycles = near-free).
//   Epilogue: kl-butterfly(1,2,4); kl==0 lanes store P[b][chunk][kqr][64][32].
// k1c: 256 blocks: sum 4 quarters -> argmax -> buckets + 64-chunk hist.
// k2/k3: 64-token-chunk scan + stable scatter (verified round 1, verbatim).

#define B_DIM 4
#define S_LEN 4096
#define D_DIM 1024
#define NRR 32
#define NBK 64
#define TMK 64                  // tokens per chunk (= hist chunk)
#define NCHUNK (S_LEN / TMK)    // 64
#define NKQ 4                   // K quarters
#define QOFF 2048               // f4 offset of Q buffers (R quarter first)
#define PSL 2048                // f32 per (block) partial slice: 64 tok x 32 r

typedef const __attribute__((address_space(1))) void* gas_t;
typedef __attribute__((address_space(3))) void* las_t;

#define FMA4(A, S, B)                                                        \
    (A).x = fmaf((S), (B).x, (A).x); (A).y = fmaf((S), (B).y, (A).y);        \
    (A).z = fmaf((S), (B).z, (A).z); (A).w = fmaf((S), (B).w, (A).w);

__global__ void __launch_bounds__(256) __attribute__((amdgpu_waves_per_eu(2, 2)))
k1_gemm(const float* __restrict__ Q, const float* __restrict__ R,
        float4* __restrict__ P4)
{
    __shared__ float4 smem4[QOFF + 2048];   // R qtr 32KB + 4w x 2buf x 256 f4

    const int bid = blockIdx.x;
    const int kqr = bid & 3;
    const int chunk = (bid >> 2) & 63;
    const int b = bid >> 8;

    const int t = threadIdx.x;
    const int w = t >> 6;
    const int lane = t & 63;
    const int tok_t = lane >> 5;         // 2 groups x 8 tokens
    const int r_t = (lane >> 3) & 3;     // 4 groups x 8 r (2 f4)
    const int kl = lane & 7;             // 8-way k split

    const float4* Qw4 = (const float4*)(Q + ((size_t)b * S_LEN + chunk * TMK + w * 16) * D_DIM);
    const float4* Rg4 = (const float4*)(R + (size_t)b * D_DIM * NRR);

#define STAGE_R()                                                             \
    {                                                                         \
        _Pragma("unroll")                                                     \
        for (int i = 0; i < 8; ++i) {                                         \
            const int rel = w * 512 + i * 64 + lane;                          \
            const int kh = rel >> 3, v = rel & 7;                             \
            __builtin_amdgcn_global_load_lds(                                 \
                (gas_t)(Rg4 + ((size_t)kqr * 256 + kh) * 8 + (v ^ ((kh >> 3) & 7))), \
                (las_t)&smem4[w * 512 + i * 64], 16, 0, 0);                   \
        }                                                                     \
    }

#define ISSUE_Q(TILE, DST)                                                    \
    {                                                                         \
        _Pragma("unroll")                                                     \
        for (int i = 0; i < 4; ++i) {                                         \
            const int f = i * 64 + lane;                                      \
            const int td = f >> 4, sd = f & 15;                               \
            __builtin_amdgcn_global_load_lds(                                 \
                (gas_t)(Qw4 + (size_t)td * 256 + kqr * 64 + (TILE) * 16       \
                        + (sd ^ (td >> 3))),                                  \
                (las_t)&smem4[QOFF + w * 512 + (DST) * 256 + i * 64], 16, 0, 0);\
        }                                                                     \
    }

#define COMPUTE(TILE, BUF)                                                    \
    {                                                                         \
        const float4* qb = smem4 + QOFF + w * 512 + (BUF) * 256;              \
        const float4* rb = smem4;                                             \
        _Pragma("unroll")                                                     \
        for (int kap = 0; kap < 2; ++kap) {                                   \
            float4 qv[8];                                                     \
            _Pragma("unroll")                                                 \
            for (int j = 0; j < 8; ++j)                                       \
                qv[j] = qb[(tok_t * 8 + j) * 16 + (((kl << 1) + kap) ^ tok_t)];\
            _Pragma("unroll")                                                 \
            for (int c = 0; c < 4; ++c) {                                     \
                const int krow = (TILE) * 64 + kl * 8 + kap * 4 + c;          \
                const float4 rv0 = rb[krow * 8 + ((r_t * 2 + 0) ^ kl)];       \
                const float4 rv1 = rb[krow * 8 + ((r_t * 2 + 1) ^ kl)];       \
                _Pragma("unroll")                                             \
                for (int j = 0; j < 8; ++j) {                                 \
                    const float s = c == 0 ? qv[j].x : c == 1 ? qv[j].y       \
                                  : c == 2 ? qv[j].z : qv[j].w;               \
                    FMA4(acc[j][0], s, rv0);                                  \
                    FMA4(acc[j][1], s, rv1);                                  \
                }                                                             \
            }                                                                 \
        }                                                                     \
    }

    float4 acc[8][2];
#pragma unroll
    for (int j = 0; j < 8; ++j) {
        acc[j][0] = make_float4(0.f, 0.f, 0.f, 0.f);
        acc[j][1] = make_float4(0.f, 0.f, 0.f, 0.f);
    }

    // prologue: R quarter (shared) + Q tile 0; the only barrier in the kernel
    STAGE_R()
    ISSUE_Q(0, 0)
    asm volatile("s_waitcnt vmcnt(0)" ::: "memory");
    __syncthreads();

#pragma unroll
    for (int tau = 0; tau < 4; ++tau) {
        if (tau + 1 < 4) {
            // prior compute's ds_reads of the dest buffer are complete
            asm volatile("s_waitcnt lgkmcnt(0)" ::: "memory");
            ISSUE_Q(tau + 1, (tau + 1) & 1)
        }
        COMPUTE(tau, tau & 1)
        // my next-tile DMAs landed (wave-private pacing, no barrier)
        asm volatile("s_waitcnt vmcnt(0)" ::: "memory");
    }
#undef STAGE_R
#undef ISSUE_Q
#undef COMPUTE

    // ---- butterfly reduce over kl (lane bits 0-2) ----
#pragma unroll
    for (int j = 0; j < 8; ++j)
#pragma unroll
        for (int p = 0; p < 2; ++p)
#pragma unroll
            for (int off = 1; off < 8; off <<= 1) {
                acc[j][p].x += __shfl_xor(acc[j][p].x, off, 64);
                acc[j][p].y += __shfl_xor(acc[j][p].y, off, 64);
                acc[j][p].z += __shfl_xor(acc[j][p].z, off, 64);
                acc[j][p].w += __shfl_xor(acc[j][p].w, off, 64);
            }

    // ---- kl==0 lanes hold full quarter-sums: store partial slice ----
    if (kl == 0) {
        float4* Pb = P4 + (((size_t)b * NCHUNK + chunk) * NKQ + kqr) * (PSL / 4);
#pragma unroll
        for (int j = 0; j < 8; ++j) {
            const int tok = w * 16 + tok_t * 8 + j;
            Pb[tok * 8 + r_t * 2 + 0] = acc[j][0];
            Pb[tok * 8 + r_t * 2 + 1] = acc[j][1];
        }
    }
}

// 256 blocks = (b, 64-token chunk): sum 4 K-quarters, argmax, bucket, hist.
__global__ __launch_bounds__(256) void k1c_combine(
    const float* __restrict__ P,
    int* __restrict__ buckets, int* __restrict__ hist)
{
    __shared__ float xs[TMK][NRR + 1];
    __shared__ int cnt[NBK];

    const int bid = blockIdx.x;
    const int b = bid >> 6;
    const int h = bid & 63;
    const int t = threadIdx.x;

    const float* Pb = P + ((size_t)b * NCHUNK + h) * NKQ * PSL;
#pragma unroll
    for (int i = 0; i < 8; ++i) {
        const int idx = t + 256 * i;          // 0..2047 = 64 tok x 32 r
        const int tok = idx >> 5, r = idx & 31;
        const size_t base = (size_t)tok * NRR + r;
        xs[tok][r] = Pb[base] + Pb[base + PSL] + Pb[base + 2 * PSL] + Pb[base + 3 * PSL];
    }
    if (t < NBK) cnt[t] = 0;
    __syncthreads();

    if (t < TMK) {
        // argmax(concat[xR,-xR]) with first-occurrence tie-break
        float m1 = xs[t][0]; int i1 = 0;
        float m2 = m1;       int i2 = 0;
#pragma unroll
        for (int r = 1; r < NRR; ++r) {
            const float v = xs[t][r];
            if (v > m1) { m1 = v; i1 = r; }
            if (v < m2) { m2 = v; i2 = r; }
        }
        const int bk = (m1 >= -m2) ? i1 : (NRR + i2);
        buckets[(size_t)b * S_LEN + h * TMK + t] = bk;
        atomicAdd(&cnt[bk], 1);
    }
    __syncthreads();
    if (t < NBK) hist[((size_t)b * NCHUNK + h) * NBK + t] = cnt[t];
}

// One block, 256 threads: thread = (batch b = t/64, bucket bk = t%64).
__global__ __launch_bounds__(256) void k2_scan(
    const int* __restrict__ hist, int* __restrict__ chunkOffset)
{
    const int t = threadIdx.x;
    const int b = t >> 6;
    const int bk = t & 63;
    const int lane = t & 63;

    int total = 0;
    for (int c = 0; c < NCHUNK; ++c)
        total += hist[((size_t)b * NCHUNK + c) * NBK + bk];

    int incl = total;
#pragma unroll
    for (int off = 1; off < 64; off <<= 1) {
        int n = __shfl_up(incl, off, 64);
        if (lane >= off) incl += n;
    }
    int run = incl - total;   // exclusive prefix over buckets = bucketStart

    for (int c = 0; c < NCHUNK; ++c) {
        int h = hist[((size_t)b * NCHUNK + c) * NBK + bk];
        chunkOffset[((size_t)b * NCHUNK + c) * NBK + bk] = run;
        run += h;
    }
}

// Stable scatter: wave = 64 consecutive tokens (one chunk).
__global__ __launch_bounds__(256) void k3_scatter(
    const int* __restrict__ buckets, const int* __restrict__ chunkOffset,
    int* __restrict__ out)
{
    const int gid = blockIdx.x * 256 + threadIdx.x;  // 0..16383
    const int b = gid >> 12;
    const int s = gid & (S_LEN - 1);
    const int chunk = s >> 6;
    const int lane = threadIdx.x & 63;

    const int bk = buckets[gid];

    unsigned long long m = ~0ull;
#pragma unroll
    for (int i = 0; i < 6; ++i) {
        unsigned long long bi = __ballot((bk >> i) & 1);
        m &= ((bk >> i) & 1) ? bi : ~bi;
    }
    int rank = __popcll(m & ((1ull << lane) - 1ull));

    int pos = chunkOffset[((size_t)b * NCHUNK + chunk) * NBK + bk] + rank;
    out[(size_t)b * S_LEN + pos] = s;
}

extern "C" void kernel_launch(void* const* d_in, const int* in_sizes, int n_in,
                              void* d_out, int out_size, void* d_ws, size_t ws_size,
                              hipStream_t stream) {
    const float* Q = (const float*)d_in[0];
    // d_in[1] = key, d_in[2] = value: dead code in the reference, never read.
    const float* R = (const float*)d_in[3];

    float* P         = (float*)d_ws;   // 4*64*4*2048 f32 = 8 MB partials
    int* buckets     = (int*)(P + (size_t)B_DIM * NCHUNK * NKQ * PSL);
    int* hist        = buckets + B_DIM * S_LEN;
    int* chunkOffset = hist + B_DIM * NCHUNK * NBK;

    k1_gemm    <<<B_DIM * NCHUNK * NKQ, 256, 0, stream>>>(Q, R, (float4*)P);
    k1c_combine<<<B_DIM * NCHUNK,       256, 0, stream>>>(P, buckets, hist);
    k2_scan    <<<1,                    256, 0, stream>>>(hist, chunkOffset);
    k3_scatter <<<(B_DIM * S_LEN) / 256, 256, 0, stream>>>(buckets, chunkOffset, (int*)d_out);
}